// Round 11
// baseline (215.194 us; speedup 1.0000x reference)
//
#include <hip/hip_runtime.h>

#define NB 256
#define NL 512
#define NI 32
#define NH 16
#define NG 64
#define SIGD 4368
#define XS 516   // xwT row stride (floats)

__device__ __forceinline__ float RL(float v, int lane) {
  return __builtin_bit_cast(float, __builtin_amdgcn_readlane(__builtin_bit_cast(int, v), lane));
}
template<int CTRL>
__device__ __forceinline__ float QB(float v) {
  // quad_perm broadcast within each 4-lane quad (VALU DPP, no LDS)
  return __builtin_bit_cast(float, __builtin_amdgcn_update_dpp(
      0, __builtin_bit_cast(int, v), CTRL, 0xF, 0xF, true));
}
__device__ __forceinline__ int cut4(int k) {
  // 4 chunks: wave0 gets tiny chunk 0 (post-LSTM); waves 1-3 stream 1,2,3.
  switch (k) {
    case 1: return 24;  case 2: return 186; case 3: return 348; case 4: return 511;
    default: return 0;
  }
}

// 256 threads = 4 waves. Wave0 (SIMD0) runs the LSTM with NO co-resident
// compute wave on its SIMD; waves 1-3 (SIMDs 1-3) stream signature chunks.
__global__ __launch_bounds__(256, 1) void k_main(const float* __restrict__ X,
    const float* __restrict__ Wih, const float* __restrict__ bih,
    const float* __restrict__ bhh, const float* __restrict__ Whh,
    const float* __restrict__ fcw, const float* __restrict__ fcb,
    float* __restrict__ out) {
  __shared__ __align__(16) float xwT[NG * XS];    // 132,096 B
  __shared__ __align__(16) float bnd[80];         // 5 boundary rows; later 4x10 FC partials
  __shared__ int prog;
  int tid = threadIdx.x;
  int wv = tid >> 6;       // 0..3
  int ln = tid & 63;
  int b = blockIdx.x;

  if (tid == 0) prog = -1;

  // ---- Phase 0: xwT[g][t] = K_g * (X[b,t,:]·W_ih[g,:] + b_ih[g] + b_hh[g]).
  // 4 waves x 128 rows. Lane = gate. X loads wave-uniform (one line per row).
  {
    const float Kg = (ln >= 32 && ln < 48) ? 2.885390082f : -1.442695041f;
    float w2[NI];
#pragma unroll
    for (int i = 0; i < 8; ++i) {
      float4 v = *(const float4*)(Wih + ln * NI + 4 * i);
      w2[4*i+0] = v.x; w2[4*i+1] = v.y; w2[4*i+2] = v.z; w2[4*i+3] = v.w;
    }
    float bias = bih[ln] + bhh[ln];
    const float* xb = X + (size_t)b * NL * NI;
#pragma unroll 4
    for (int t = 128 * wv; t < 128 * (wv + 1); ++t) {
      const float4* xr = (const float4*)(xb + t * NI);
      float x0 = bias, x1 = 0.f, x2 = 0.f, x3 = 0.f;
#pragma unroll
      for (int i = 0; i < 8; ++i) {
        float4 xv = xr[i];
        x0 += xv.x * w2[4*i+0]; x1 += xv.y * w2[4*i+1];
        x2 += xv.z * w2[4*i+2]; x3 += xv.w * w2[4*i+3];
      }
      xwT[ln * XS + t] = Kg * ((x0 + x1) + (x2 + x3));   // K pre-folded
    }
  }
  __syncthreads();

  // ---- Phase A (wave 0, exclusive on SIMD0): LSTM, quad layout.
  if (wv == 0) {
    __asm__ __volatile__("s_setprio 3");
    const int q = ln & 3;
    const int j = ln >> 2;
    const int gmem = q * 16 + j;
    const bool isg = (q == 2);
    const float Kg = isg ? 2.885390082f : -1.442695041f;
    const float Av = isg ? -2.0f : 1.0f;
    const float Bv = isg ? 1.0f : 0.0f;
    const float CT = 2.885390082f;
    float w[NH];                               // K-scaled W_hh row
#pragma unroll
    for (int qq = 0; qq < 4; ++qq) {
      float4 v = *(const float4*)(Whh + gmem * NH + 4 * qq);
      w[4*qq+0] = Kg*v.x; w[4*qq+1] = Kg*v.y; w[4*qq+2] = Kg*v.z; w[4*qq+3] = Kg*v.w;
    }
    const float* xt = xwT + gmem * XS;
    float4 xq[4];                              // 16 steps of K-scaled xval in flight
#pragma unroll
    for (int i = 0; i < 4; ++i) xq[i] = *(const float4*)(xt + 4 * i);
    float cs = 0.0f, hval = 0.0f;              // cs = CT * c
    for (int tb = 0; tb < NL; tb += 16) {
#pragma unroll
      for (int k = 0; k < 16; ++k) {
        int t = tb + k;
        float hs[16];
#pragma unroll
        for (int u = 0; u < 16; ++u) hs[u] = RL(hval, 4 * u);
        float xval = ((const float*)xq)[k];    // consume before refill
        if ((k & 3) == 3 && t + 16 < NL)
          xq[k >> 2] = *(const float4*)(xt + (t + 13));
        float a0 = xval, a1 = 0.f, a2 = 0.f, a3 = 0.f;
#pragma unroll
        for (int u = 0; u < 4; ++u) {
          a0 += hs[4*u+0] * w[4*u+0];
          a1 += hs[4*u+1] * w[4*u+1];
          a2 += hs[4*u+2] * w[4*u+2];
          a3 += hs[4*u+3] * w[4*u+3];
        }
        float acc = (a0 + a1) + (a2 + a3);     // already K-scaled
        float e = __builtin_amdgcn_exp2f(acc);
        float r = __builtin_amdgcn_rcpf(1.0f + e);
        float val = __builtin_fmaf(Av, r, Bv);
        float iv = QB<0x00>(val);
        float fv = QB<0x55>(val);
        float gv = QB<0xAA>(val);
        float ov = QB<0xFF>(val);
        cs = __builtin_fmaf(fv, cs, (CT * iv) * gv);
        float e2 = __builtin_amdgcn_exp2f(cs);
        float tc = __builtin_fmaf(-2.0f, __builtin_amdgcn_rcpf(1.0f + e2), 1.0f);
        hval = ov * tc;
        if (q == 0) xwT[j * XS + t] = hval;    // 16 lanes, 2-way banks (free)
      }
      __asm__ __volatile__("" ::: "memory");
      if (ln == 0) *(volatile int*)&prog = tb + 15;
    }
    __asm__ __volatile__("s_setprio 0");
  }

  // ---- Phase B: signature chunks. Waves 1-3 STREAM rows as wave0 publishes;
  // wave0 does the 24-row chunk 0 after the LSTM (all rows present).
  const int bi = ln & 15;
  const int hi = ln >> 4;
  const int ch = wv;
  int ts = cut4(ch);
  int te = cut4(ch + 1);
  while (*(volatile int*)&prog < ts) __builtin_amdgcn_s_sleep(4);
  __asm__ __volatile__("" ::: "memory");

  float s3[4][16];
  float s2[4] = {0.f, 0.f, 0.f, 0.f};
#pragma unroll
  for (int m = 0; m < 4; ++m)
#pragma unroll
    for (int cc = 0; cc < 16; ++cc) s3[m][cc] = 0.f;
  float hc[16];
#pragma unroll
  for (int cc = 0; cc < 16; ++cc) hc[cc] = xwT[cc * XS + ts];   // uniform reads
  float hcb = xwT[bi * XS + ts];
  float hca[4], h0a[4];
#pragma unroll
  for (int m = 0; m < 4; ++m) { hca[m] = xwT[(4 * m + hi) * XS + ts]; h0a[m] = hca[m]; }
  for (int t = ts; t < te; ++t) {
    int tn = t + 1;
    while (*(volatile int*)&prog < tn) __builtin_amdgcn_s_sleep(2);  // stream
    __asm__ __volatile__("" ::: "memory");
    float hn[16];
#pragma unroll
    for (int cc = 0; cc < 16; ++cc) hn[cc] = xwT[cc * XS + tn];
    float hnb = xwT[bi * XS + tn];
    float d[16];
#pragma unroll
    for (int cc = 0; cc < 16; ++cc) d[cc] = hn[cc] - hc[cc];
    float db = hnb - hcb;
    float P[4];
#pragma unroll
    for (int m = 0; m < 4; ++m) {
      float hna = xwT[(4 * m + hi) * XS + tn];
      float da = hna - hca[m];
      float s1 = hca[m] - h0a[m];                      // S1[a] pre-increment (telescoping)
      P[m] = s2[m] + db * (0.5f * s1 + 0.166666666667f * da);
      s2[m] += db * (s1 + 0.5f * da);                  // S2 += e2 + S1(x)e1
      hca[m] = hna;
    }
#pragma unroll
    for (int m = 0; m < 4; ++m)
#pragma unroll
      for (int cc = 0; cc < 16; ++cc)
        s3[m][cc] += P[m] * d[cc];                     // S3 += e3 + S2(x)e1 + S1(x)e2
#pragma unroll
    for (int cc = 0; cc < 16; ++cc) hc[cc] = hn[cc];
    hcb = hnb;
  }
  __syncthreads();

  // save boundary rows h[cut4(k)] (k=0..4) before slots overwrite the region
  if (tid < 80) {
    int k = tid >> 4, j = tid & 15;
    bnd[tid] = xwT[j * XS + cut4(k)];
  }
  __syncthreads();

  // ---- Phase C: Chen tree-combine, 2 levels (4 chunks), slots overlay xwT.
  float* slot0 = xwT;
  float* slot1 = xwT + 4352;
  float* sigb  = xwT + 8704;
  auto writeSlot = [&](float* slot) {
#pragma unroll
    for (int m = 0; m < 4; ++m) slot[64 * m + ln] = s2[m];  // index == a*16+b
    float* s3s = slot + 256;
#pragma unroll
    for (int m = 0; m < 4; ++m)
#pragma unroll
      for (int cc = 0; cc < 16; ++cc)
        s3s[64 * ln + ((m * 16 + cc) ^ (ln & 31))] = s3[m][cc];
  };
  auto combineSlot = [&](const float* slot, int as_, int ae_, int bs_, int be_) {
    const float* s2b = slot;
    const float* s3b = slot + 256;
    float s1b[16];
#pragma unroll
    for (int cc = 0; cc < 16; ++cc) s1b[cc] = bnd[be_ * 16 + cc] - bnd[bs_ * 16 + cc];
    float s1bb = bnd[be_ * 16 + bi] - bnd[bs_ * 16 + bi];
    float s1aa[4];
#pragma unroll
    for (int m = 0; m < 4; ++m) {
      int a = 4 * m + hi;
      s1aa[m] = bnd[ae_ * 16 + a] - bnd[as_ * 16 + a];
    }
    float row[16];
#pragma unroll
    for (int cc = 0; cc < 16; ++cc) row[cc] = s2b[bi * 16 + cc];
#pragma unroll
    for (int m = 0; m < 4; ++m) {
      float s2bo = s2b[64 * m + ln];
#pragma unroll
      for (int cc = 0; cc < 16; ++cc)
        s3[m][cc] += s3b[64 * ln + ((m * 16 + cc) ^ (ln & 31))]
                   + s2[m] * s1b[cc] + s1aa[m] * row[cc];   // uses OLD s2 (S2a)
      s2[m] += s2bo + s1aa[m] * s1bb;
    }
  };
  // Level 1: (0,1) and (2,3)
  if (ch == 1) writeSlot(slot0);
  if (ch == 3) writeSlot(slot1);
  __syncthreads();
  if (ch == 0) combineSlot(slot0, 0, 1, 1, 2);
  if (ch == 2) combineSlot(slot1, 2, 3, 3, 4);
  __syncthreads();
  // Level 2: (01, 23)
  if (ch == 2) writeSlot(slot0);
  __syncthreads();
  if (ch == 0) {
    combineSlot(slot0, 0, 2, 2, 4);
    // write sig = [S1(16) | S2(256) | S3(4096)] into LDS sig buffer
    if (ln < 16) sigb[ln] = bnd[4 * 16 + ln] - bnd[ln];   // S1 = h[511]-h[0]
#pragma unroll
    for (int m = 0; m < 4; ++m) sigb[16 + 64 * m + ln] = s2[m];
#pragma unroll
    for (int m = 0; m < 4; ++m) {
#pragma unroll
      for (int qq = 0; qq < 4; ++qq) {
        float4 v;
        v.x = s3[m][4*qq+0]; v.y = s3[m][4*qq+1]; v.z = s3[m][4*qq+2]; v.w = s3[m][4*qq+3];
        *(float4*)(sigb + 272 + 1024 * m + 256 * hi + 16 * bi + 4 * qq) = v;
      }
    }
  }
  __syncthreads();

  // ---- Phase D: FC. out[b][o] = sig·fc_w[o] + fc_b[o], 256 threads.
  {
    float acc[10];
#pragma unroll
    for (int o = 0; o < 10; ++o) acc[o] = 0.f;
    for (int k = tid; k < SIGD; k += 256) {
      float s = sigb[k];
#pragma unroll
      for (int o = 0; o < 10; ++o) acc[o] += s * fcw[o * SIGD + k];
    }
#pragma unroll
    for (int o = 0; o < 10; ++o) {
      float v = acc[o];
#pragma unroll
      for (int off = 32; off > 0; off >>= 1) v += __shfl_down(v, off);
      if (ln == 0) bnd[wv * 10 + o] = v;    // bnd dead after phase C
    }
    __syncthreads();
    if (tid < 10) {
      float s = fcb[tid];
#pragma unroll
      for (int w = 0; w < 4; ++w) s += bnd[w * 10 + tid];
      out[b * 10 + tid] = s;
    }
  }
}

extern "C" void kernel_launch(void* const* d_in, const int* in_sizes, int n_in,
                              void* d_out, int out_size, void* d_ws, size_t ws_size,
                              hipStream_t stream) {
  const float* X   = (const float*)d_in[0];
  const float* Wih = (const float*)d_in[1];
  const float* Whh = (const float*)d_in[2];
  const float* bih = (const float*)d_in[3];
  const float* bhh = (const float*)d_in[4];
  const float* fcw = (const float*)d_in[5];
  const float* fcb = (const float*)d_in[6];
  float* out = (float*)d_out;
  k_main<<<NB, 256, 0, stream>>>(X, Wih, bih, bhh, Whh, fcw, fcb, out);
}

// Round 12
// 197.334 us; speedup vs baseline: 1.0905x; 1.0905x over previous
//
#include <hip/hip_runtime.h>

#define NB 256
#define NL 512
#define NI 32
#define NH 16
#define NG 64
#define SIGD 4368
#define XS 516   // xwT row stride (floats): pad -> strided access lands 2-way (free)

__device__ __forceinline__ float RL(float v, int lane) {
  return __builtin_bit_cast(float, __builtin_amdgcn_readlane(__builtin_bit_cast(int, v), lane));
}
template<int CTRL>
__device__ __forceinline__ float QB(float v) {
  // quad_perm broadcast within each 4-lane quad (VALU DPP, no LDS)
  return __builtin_bit_cast(float, __builtin_amdgcn_update_dpp(
      0, __builtin_bit_cast(int, v), CTRL, 0xF, 0xF, true));
}
__device__ __forceinline__ int cutf(int k) {
  switch (k) {
    case 1: return 24;  case 2: return 102; case 3: return 180; case 4: return 258;
    case 5: return 335; case 6: return 412; case 7: return 488; case 8: return 511;
    default: return 0;
  }
}

// Single kernel (R10 config — best measured). Phase 0: xw -> LDS transposed,
// pre-scaled by K_g. Phase A: wave0 LSTM (K-scaled weights, batched readlanes,
// scaled-c recurrence, guarded h-store). Phase B: chunked signatures on 8
// waves. Phase C: Chen tree-combine. Phase D: FC epilogue.
__global__ __launch_bounds__(512, 1) void k_main(const float* __restrict__ X,
    const float* __restrict__ Wih, const float* __restrict__ bih,
    const float* __restrict__ bhh, const float* __restrict__ Whh,
    const float* __restrict__ fcw, const float* __restrict__ fcb,
    float* __restrict__ out) {
  __shared__ __align__(16) float xwT[NG * XS];    // 132,096 B
  __shared__ __align__(16) float bnd[144];
  __shared__ int prog;
  int tid = threadIdx.x;
  int wv = tid >> 6;
  int ln = tid & 63;
  int b = blockIdx.x;

  if (tid == 0) prog = -1;

  // ---- Phase 0: xwT[g][t] = K_g * (X[b,t,:]·W_ih[g,:] + b_ih[g] + b_hh[g]).
  {
    const float Kg = (ln >= 32 && ln < 48) ? 2.885390082f : -1.442695041f;
    float w2[NI];
#pragma unroll
    for (int i = 0; i < 8; ++i) {
      float4 v = *(const float4*)(Wih + ln * NI + 4 * i);
      w2[4*i+0] = v.x; w2[4*i+1] = v.y; w2[4*i+2] = v.z; w2[4*i+3] = v.w;
    }
    float bias = bih[ln] + bhh[ln];
    const float* xb = X + (size_t)b * NL * NI;
#pragma unroll 4
    for (int t = 64 * wv; t < 64 * (wv + 1); ++t) {
      const float4* xr = (const float4*)(xb + t * NI);
      float x0 = bias, x1 = 0.f, x2 = 0.f, x3 = 0.f;
#pragma unroll
      for (int i = 0; i < 8; ++i) {
        float4 xv = xr[i];
        x0 += xv.x * w2[4*i+0]; x1 += xv.y * w2[4*i+1];
        x2 += xv.z * w2[4*i+2]; x3 += xv.w * w2[4*i+3];
      }
      xwT[ln * XS + t] = Kg * ((x0 + x1) + (x2 + x3));   // K pre-folded
    }
  }
  __syncthreads();

  // ---- Phase A (wave 0): LSTM, quad layout. lane = 4*unit + gate_type (i,f,g,o).
  if (wv == 0) {
    __asm__ __volatile__("s_setprio 3");
    const int q = ln & 3;
    const int j = ln >> 2;
    const int gmem = q * 16 + j;
    const bool isg = (q == 2);
    const float Kg = isg ? 2.885390082f : -1.442695041f;
    const float Av = isg ? -2.0f : 1.0f;
    const float Bv = isg ? 1.0f : 0.0f;
    const float CT = 2.885390082f;
    float w[NH];                               // K-scaled W_hh row
#pragma unroll
    for (int qq = 0; qq < 4; ++qq) {
      float4 v = *(const float4*)(Whh + gmem * NH + 4 * qq);
      w[4*qq+0] = Kg*v.x; w[4*qq+1] = Kg*v.y; w[4*qq+2] = Kg*v.z; w[4*qq+3] = Kg*v.w;
    }
    const float* xt = xwT + gmem * XS;
    float4 xq[4];                              // 16 steps of K-scaled xval in flight
#pragma unroll
    for (int i = 0; i < 4; ++i) xq[i] = *(const float4*)(xt + 4 * i);
    float cs = 0.0f, hval = 0.0f;              // cs = CT * c  (scaled cell state)
    for (int tb = 0; tb < NL; tb += 16) {
#pragma unroll
      for (int k = 0; k < 16; ++k) {
        int t = tb + k;
        // batched readlanes: all 16 h broadcasts BEFORE any FMA (hazard x1)
        float hs[16];
#pragma unroll
        for (int u = 0; u < 16; ++u) hs[u] = RL(hval, 4 * u);
        float xval = ((const float*)xq)[k];    // consume before refill (R8 fix)
        if ((k & 3) == 3 && t + 16 < NL)
          xq[k >> 2] = *(const float4*)(xt + (t + 13));
        float a0 = xval, a1 = 0.f, a2 = 0.f, a3 = 0.f;
#pragma unroll
        for (int u = 0; u < 4; ++u) {
          a0 += hs[4*u+0] * w[4*u+0];
          a1 += hs[4*u+1] * w[4*u+1];
          a2 += hs[4*u+2] * w[4*u+2];
          a3 += hs[4*u+3] * w[4*u+3];
        }
        float acc = (a0 + a1) + (a2 + a3);     // already K-scaled
        float e = __builtin_amdgcn_exp2f(acc);
        float r = __builtin_amdgcn_rcpf(1.0f + e);
        float val = __builtin_fmaf(Av, r, Bv);
        float iv = QB<0x00>(val);
        float fv = QB<0x55>(val);
        float gv = QB<0xAA>(val);
        float ov = QB<0xFF>(val);
        cs = __builtin_fmaf(fv, cs, (CT * iv) * gv);   // scaled-c recurrence
        float e2 = __builtin_amdgcn_exp2f(cs);
        float tc = __builtin_fmaf(-2.0f, __builtin_amdgcn_rcpf(1.0f + e2), 1.0f);
        hval = ov * tc;
        if (q == 0) xwT[j * XS + t] = hval;    // guarded: 16 lanes, distinct banks
      }
      __asm__ __volatile__("" ::: "memory");
      if (ln == 0) *(volatile int*)&prog = tb + 15;
    }
    __asm__ __volatile__("s_setprio 0");
  }

  // ---- Phase B: chunked signatures (h row t: h[t][j] = xwT[j*XS + t]).
  const int bi = ln & 15;
  const int hi = ln >> 4;
  const int ch = wv;
  int ts = cutf(ch);
  int te = cutf(ch + 1);
  while (*(volatile int*)&prog < te) __builtin_amdgcn_s_sleep(8);
  __asm__ __volatile__("" ::: "memory");

  float s3[4][16];
  float s2[4] = {0.f, 0.f, 0.f, 0.f};
#pragma unroll
  for (int m = 0; m < 4; ++m)
#pragma unroll
    for (int cc = 0; cc < 16; ++cc) s3[m][cc] = 0.f;
  float hc[16];
#pragma unroll
  for (int cc = 0; cc < 16; ++cc) hc[cc] = xwT[cc * XS + ts];   // uniform reads
  float hcb = xwT[bi * XS + ts];
  float hca[4], h0a[4];
#pragma unroll
  for (int m = 0; m < 4; ++m) { hca[m] = xwT[(4 * m + hi) * XS + ts]; h0a[m] = hca[m]; }
  for (int t = ts; t < te; ++t) {
    int tn = t + 1;
    float hn[16];
#pragma unroll
    for (int cc = 0; cc < 16; ++cc) hn[cc] = xwT[cc * XS + tn];
    float hnb = xwT[bi * XS + tn];
    float d[16];
#pragma unroll
    for (int cc = 0; cc < 16; ++cc) d[cc] = hn[cc] - hc[cc];
    float db = hnb - hcb;
    float P[4];
#pragma unroll
    for (int m = 0; m < 4; ++m) {
      float hna = xwT[(4 * m + hi) * XS + tn];
      float da = hna - hca[m];
      float s1 = hca[m] - h0a[m];                      // S1[a] pre-increment (telescoping)
      P[m] = s2[m] + db * (0.5f * s1 + 0.166666666667f * da);
      s2[m] += db * (s1 + 0.5f * da);                  // S2 += e2 + S1(x)e1
      hca[m] = hna;
    }
#pragma unroll
    for (int m = 0; m < 4; ++m)
#pragma unroll
      for (int cc = 0; cc < 16; ++cc)
        s3[m][cc] += P[m] * d[cc];                     // S3 += e3 + S2(x)e1 + S1(x)e2
#pragma unroll
    for (int cc = 0; cc < 16; ++cc) hc[cc] = hn[cc];
    hcb = hnb;
  }
  __syncthreads();

  // save boundary rows h[cut(k)][j] (k=0..8) before slots overwrite the region
  if (tid < 144) {
    int k = tid >> 4, j = tid & 15;
    bnd[tid] = xwT[j * XS + cutf(k)];
  }
  __syncthreads();

  // ---- Phase C: Chen tree-combine via 2 LDS slots (overlay dead xwT region).
  float* slot0 = xwT;
  float* slot1 = xwT + 4352;
  float* sigb  = xwT + 8704;
  auto writeSlot = [&](float* slot) {
#pragma unroll
    for (int m = 0; m < 4; ++m) slot[64 * m + ln] = s2[m];  // index == a*16+b
    float* s3s = slot + 256;
#pragma unroll
    for (int m = 0; m < 4; ++m)
#pragma unroll
      for (int cc = 0; cc < 16; ++cc)
        s3s[64 * ln + ((m * 16 + cc) ^ (ln & 31))] = s3[m][cc];
  };
  auto combineSlot = [&](const float* slot, int as_, int ae_, int bs_, int be_) {
    const float* s2b = slot;
    const float* s3b = slot + 256;
    float s1b[16];
#pragma unroll
    for (int cc = 0; cc < 16; ++cc) s1b[cc] = bnd[be_ * 16 + cc] - bnd[bs_ * 16 + cc];
    float s1bb = bnd[be_ * 16 + bi] - bnd[bs_ * 16 + bi];
    float s1aa[4];
#pragma unroll
    for (int m = 0; m < 4; ++m) {
      int a = 4 * m + hi;
      s1aa[m] = bnd[ae_ * 16 + a] - bnd[as_ * 16 + a];
    }
    float row[16];
#pragma unroll
    for (int cc = 0; cc < 16; ++cc) row[cc] = s2b[bi * 16 + cc];
#pragma unroll
    for (int m = 0; m < 4; ++m) {
      float s2bo = s2b[64 * m + ln];
#pragma unroll
      for (int cc = 0; cc < 16; ++cc)
        s3[m][cc] += s3b[64 * ln + ((m * 16 + cc) ^ (ln & 31))]
                   + s2[m] * s1b[cc] + s1aa[m] * row[cc];   // uses OLD s2 (S2a)
      s2[m] += s2bo + s1aa[m] * s1bb;
    }
  };
  // Round 1a: chunks (0,1) and (2,3)
  if (ch == 1) writeSlot(slot0);
  if (ch == 3) writeSlot(slot1);
  __syncthreads();
  if (ch == 0) combineSlot(slot0, 0, 1, 1, 2);
  if (ch == 2) combineSlot(slot1, 2, 3, 3, 4);
  __syncthreads();
  // Round 1b: chunks (4,5) and (6,7)
  if (ch == 5) writeSlot(slot0);
  if (ch == 7) writeSlot(slot1);
  __syncthreads();
  if (ch == 4) combineSlot(slot0, 4, 5, 5, 6);
  if (ch == 6) combineSlot(slot1, 6, 7, 7, 8);
  __syncthreads();
  // Round 2: (01,23) and (45,67)
  if (ch == 2) writeSlot(slot0);
  if (ch == 6) writeSlot(slot1);
  __syncthreads();
  if (ch == 0) combineSlot(slot0, 0, 2, 2, 4);
  if (ch == 4) combineSlot(slot1, 4, 6, 6, 8);
  __syncthreads();
  // Round 3: (0123, 4567)
  if (ch == 4) writeSlot(slot0);
  __syncthreads();
  if (ch == 0) {
    combineSlot(slot0, 0, 4, 4, 8);
    if (ln < 16) sigb[ln] = bnd[8 * 16 + ln] - bnd[ln];   // S1 = h[511]-h[0]
#pragma unroll
    for (int m = 0; m < 4; ++m) sigb[16 + 64 * m + ln] = s2[m];
#pragma unroll
    for (int m = 0; m < 4; ++m) {
#pragma unroll
      for (int qq = 0; qq < 4; ++qq) {
        float4 v;
        v.x = s3[m][4*qq+0]; v.y = s3[m][4*qq+1]; v.z = s3[m][4*qq+2]; v.w = s3[m][4*qq+3];
        *(float4*)(sigb + 272 + 1024 * m + 256 * hi + 16 * bi + 4 * qq) = v;
      }
    }
  }
  __syncthreads();

  // ---- Phase D: FC. out[b][o] = sig·fc_w[o] + fc_b[o], all 512 threads.
  {
    float acc[10];
#pragma unroll
    for (int o = 0; o < 10; ++o) acc[o] = 0.f;
    for (int k = tid; k < SIGD; k += 512) {
      float s = sigb[k];
#pragma unroll
      for (int o = 0; o < 10; ++o) acc[o] += s * fcw[o * SIGD + k];
    }
#pragma unroll
    for (int o = 0; o < 10; ++o) {
      float v = acc[o];
#pragma unroll
      for (int off = 32; off > 0; off >>= 1) v += __shfl_down(v, off);
      if (ln == 0) bnd[wv * 10 + o] = v;
    }
    __syncthreads();
    if (tid < 10) {
      float s = fcb[tid];
#pragma unroll
      for (int w = 0; w < 8; ++w) s += bnd[w * 10 + tid];
      out[b * 10 + tid] = s;
    }
  }
}

extern "C" void kernel_launch(void* const* d_in, const int* in_sizes, int n_in,
                              void* d_out, int out_size, void* d_ws, size_t ws_size,
                              hipStream_t stream) {
  const float* X   = (const float*)d_in[0];
  const float* Wih = (const float*)d_in[1];
  const float* Whh = (const float*)d_in[2];
  const float* bih = (const float*)d_in[3];
  const float* bhh = (const float*)d_in[4];
  const float* fcw = (const float*)d_in[5];
  const float* fcb = (const float*)d_in[6];
  float* out = (float*)d_out;
  k_main<<<NB, 512, 0, stream>>>(X, Wih, bih, bhh, Whh, fcw, fcb, out);
}